// Round 22
// baseline (2591.825 us; speedup 1.0000x reference)
//
#include <hip/hip_runtime.h>

// ---------------- problem constants ----------------
#define Nn 200000
#define Ee 800000
#define Dd 300
#define D2 600
#define Gg 8000
#define NLAYER 5
#define HW 304               // h stored width (bf16, row-major); cols 300..303 zero
#define K2P 608              // hidden width (gemm2 K), 600 + 8 zero pad
#define ZLD 620              // zl LDS row stride: 310 dw ≡ 22 mod 32 -> balanced banks (r16)
#define MROWS 64             // fused_mlp rows per block
#define PANEL 20480          // u16 per A-panel: 64 rows x 320 k (fragment layout)
#define PW1 194560           // u16 per layer W1f: 38 frag x 10 ks x 512
#define PW2 184832           // u16 per layer W2f: 19 frag x 19 ks x 512
#define NB_SCAN 98           // ceil(Nn / 2048)

typedef unsigned short u16;
typedef unsigned int u32;
typedef __attribute__((ext_vector_type(8))) short bh8;   // 8 x bf16
typedef __attribute__((ext_vector_type(4))) float f4;
typedef __attribute__((ext_vector_type(2))) unsigned int u32x2;
typedef __attribute__((ext_vector_type(4))) unsigned int u32x4;

__device__ __forceinline__ u16 f2bf(float f) {
  union { float f; unsigned u; } x; x.f = f;
  unsigned r = x.u + 0x7FFFu + ((x.u >> 16) & 1u);   // RNE
  return (u16)(r >> 16);
}
__device__ __forceinline__ float bf2f(u16 v) {
  union { unsigned u; float f; } x; x.u = ((unsigned)v) << 16;
  return x.f;
}
// HW packed f32->bf16 (RNE): lo -> D[15:0], hi -> D[31:16]
__device__ __forceinline__ u32 cvtpk(float lo, float hi) {
  u32 r;
  asm("v_cvt_pk_bf16_f32 %0, %1, %2" : "=v"(r) : "v"(lo), "v"(hi));
  return r;
}
__device__ __forceinline__ void mfma16(f4& c, bh8 a, bh8 b) {
  asm("v_mfma_f32_16x16x32_bf16 %0, %1, %2, %0" : "+v"(c) : "v"(a), "v"(b));
}
// async global->LDS DMA, 16B/lane; dest = wave-uniform base + lane*16 (full exec!)
__device__ __forceinline__ void gl16(const u16* g, u16* l) {
  __builtin_amdgcn_global_load_lds((const __attribute__((address_space(1))) void*)g,
                                   (__attribute__((address_space(3))) void*)l, 16, 0, 0);
}

// ---------------- tiny utils ----------------
__global__ void zero_u32(u32* __restrict__ p, int n) {
  for (int i = blockIdx.x * blockDim.x + threadIdx.x; i < n; i += gridDim.x * blockDim.x)
    p[i] = 0u;
}
__global__ void probe_kernel(float* __restrict__ out, float v) {
  if (blockIdx.x == 0 && threadIdx.x == 0) out[0] = v;
}

// ---------------- CSR build ----------------
__global__ void count_kernel(const int* __restrict__ ei, u32* __restrict__ cnt) {
  for (int e = blockIdx.x * blockDim.x + threadIdx.x; e < Ee; e += gridDim.x * blockDim.x)
    atomicAdd(&cnt[ei[Ee + e]], 1u);
}
__global__ void scan1_kernel(const u32* __restrict__ cnt, u32* __restrict__ offs,
                             u32* __restrict__ bsum) {
  int b = blockIdx.x, t = threadIdx.x, lane = t & 63;
  int base = b * 2048 + t * 8;
  u32 v[8], s = 0;
#pragma unroll
  for (int j = 0; j < 8; ++j) { v[j] = (base + j < Nn) ? cnt[base + j] : 0u; s += v[j]; }
  u32 sc = s;
#pragma unroll
  for (int d = 1; d < 64; d <<= 1) { u32 o = __shfl_up(sc, d); if (lane >= d) sc += o; }
  __shared__ u32 swv[4];
  if (lane == 63) swv[t >> 6] = sc;
  __syncthreads();
  u32 wbase = 0;
  for (int w = 0; w < (t >> 6); ++w) wbase += swv[w];
  u32 run = wbase + sc - s;
#pragma unroll
  for (int j = 0; j < 8; ++j) {
    if (base + j < Nn) offs[base + j] = run;
    run += v[j];
  }
  if (t == 255) bsum[b] = wbase + sc;
}
__global__ void scan2_kernel(u32* __restrict__ bsum, u32* __restrict__ offs) {
  if (threadIdx.x == 0) {
    u32 run = 0;
    for (int b = 0; b < NB_SCAN; ++b) { u32 t = bsum[b]; bsum[b] = run; run += t; }
    offs[Nn] = (u32)Ee;
  }
}
__global__ void scan3_kernel(const u32* __restrict__ bsum, u32* __restrict__ offs) {
  int b = blockIdx.x;
  u32 add = bsum[b];
  int base = b * 2048 + threadIdx.x * 8;
#pragma unroll
  for (int j = 0; j < 8; ++j)
    if (base + j < Nn) offs[base + j] += add;
}
__global__ void scatter_kernel(const int* __restrict__ ei, const int* __restrict__ ea,
                               const u32* __restrict__ offs, u32* __restrict__ cur,
                               u32* __restrict__ eg) {
  for (int e = blockIdx.x * blockDim.x + threadIdx.x; e < Ee; e += gridDim.x * blockDim.x) {
    int dst = ei[Ee + e], src = ei[e];
    u32 pos = offs[dst] + atomicAdd(&cur[dst], 1u);
    eg[pos] = (u32)src | ((u32)ea[e * 3] << 18) | ((u32)ea[e * 3 + 1] << 22) |
              ((u32)ea[e * 3 + 2] << 26);
  }
}

// ---------------- per-layer bond sums: bndsum[a0+16a1+256a2][304] bf16 ----------------
__global__ void bsum_kernel(const float* __restrict__ bond, u16* __restrict__ bs) {
  int idx = blockIdx.x, tid = threadIdx.x;
  int a0 = idx & 15, a1 = (idx >> 4) & 15, a2 = idx >> 8;
  for (int c = tid; c < HW; c += 256) {
    float v = 0.f;
    if (c < Dd)
      v = bond[(size_t)a0 * Dd + c] + bond[4800 + (size_t)a1 * Dd + c] +
          bond[9600 + (size_t)a2 * Dd + c];
    bs[(size_t)idx * HW + c] = f2bf(v);
  }
}

// ---------------- atom encoder: Ha = bf16(sum_f atom_emb[f, x[n,f], :])
#define ABLK 2048
__global__ __launch_bounds__(256) void atom_kernel(const int* __restrict__ x,
                                                   const float* __restrict__ aemb,
                                                   u16* __restrict__ H) {
  const int wave = threadIdx.x >> 6, lane = threadIdx.x & 63;
  for (int n = blockIdx.x * 4 + wave; n < Nn; n += ABLK * 4) {
    if (lane < 38) {
      float lo[4] = {0.f, 0.f, 0.f, 0.f}, hi[4] = {0.f, 0.f, 0.f, 0.f};
#pragma unroll
      for (int f = 0; f < 9; ++f) {
        int xv = x[n * 9 + f];
        const float* e = aemb + (size_t)((f << 6) + xv) * Dd + lane * 8;
        f4 a = *(const f4*)e;
#pragma unroll
        for (int j = 0; j < 4; ++j) lo[j] += a[j];
        if (lane < 37) {                           // cols 300..303 stay zero (OOB guard)
          f4 b = *(const f4*)(e + 4);
#pragma unroll
          for (int j = 0; j < 4; ++j) hi[j] += b[j];
        }
      }
      u32x4 o;
      o[0] = cvtpk(lo[0], lo[1]); o[1] = cvtpk(lo[2], lo[3]);
      o[2] = cvtpk(hi[0], hi[1]); o[3] = cvtpk(hi[2], hi[3]);
      *(u32x4*)(H + (size_t)n * HW + lane * 8) = o;
    }
  }
}

// ---------------- prep: Ha += vfeat[batch]  (wave-per-node, vectorized)
#define PBLK 2048
__global__ __launch_bounds__(256) void prep_kernel(u16* __restrict__ H,
                                                   const float* __restrict__ vfeat,
                                                   const int* __restrict__ batch) {
  const int wave = threadIdx.x >> 6, lane = threadIdx.x & 63;
  for (int n = blockIdx.x * 4 + wave; n < Nn; n += PBLK * 4) {
    if (lane < 38) {
      const float* vf = vfeat + (size_t)batch[n] * Dd + lane * 8;
      u16* h = H + (size_t)n * HW + lane * 8;
      bh8 hv = *(const bh8*)h;
      f4 lo = *(const f4*)vf;                             // elems c..c+3 (<=299 ok)
      f4 hi = (lane < 37) ? *(const f4*)(vf + 4) : (f4){0.f, 0.f, 0.f, 0.f};
      union { bh8 v; u16 a[8]; } o;
#pragma unroll
      for (int j = 0; j < 4; ++j) o.a[j] = f2bf(bf2f((u16)hv[j]) + lo[j]);
#pragma unroll
      for (int j = 0; j < 4; ++j) o.a[4 + j] = f2bf(bf2f((u16)hv[4 + j]) + hi[j]);
      *(bh8*)h = o.v;
    }
  }
}

// ---------------- gather: Agg[n] = H[n] + sum_{e->n} relu(H[src]+bndsum) -> Hb
#define GBLK 2048
#define EDGE_ACC(ROW, BS)                                                             \
  {                                                                                   \
    _Pragma("unroll") for (int j = 0; j < 8; ++j) acc[j] +=                           \
        fmaxf(bf2f((u16)(ROW)[j]) + bf2f((u16)(BS)[j]), 0.f);                         \
  }
__global__ __launch_bounds__(256) void gather_kernel(
    const u16* __restrict__ H, const u32* __restrict__ offs, const u32* __restrict__ eg,
    const u16* __restrict__ bsumT, u16* __restrict__ Agg) {
  const int wave = threadIdx.x >> 6, lane = threadIdx.x & 63;
  const bool act = lane < 38;                      // 38*8 = 304 data cols
  const int l8 = lane * 8;
  const bh8 z8v = {0, 0, 0, 0, 0, 0, 0, 0};
  for (int n = blockIdx.x * 4 + wave; n < Nn; n += GBLK * 4) {
    const u32 lo = offs[n], hi = offs[n + 1];
    float acc[8];
    {
      bh8 hv = act ? *(const bh8*)(H + (size_t)n * HW + l8) : z8v;
#pragma unroll
      for (int j = 0; j < 8; ++j) acc[j] = bf2f((u16)hv[j]);
    }
    const int deg = (int)(hi - lo);
    u32 mypk = (lo + (u32)lane < hi) ? eg[lo + lane] : 0u;   // all edges in one load
    const int cnt = deg < 64 ? deg : 64;
    if (cnt > 0) {
      u32 pk = __shfl(mypk, 0);
      bh8 row = act ? *(const bh8*)(H + (size_t)(pk & 0x3FFFF) * HW + l8) : z8v;
      bh8 bs  = act ? *(const bh8*)(bsumT + (size_t)((pk >> 18) & 4095) * HW + l8) : z8v;
      for (int e = 1; e < cnt; ++e) {
        u32 pk2 = __shfl(mypk, e);
        bh8 row2 = act ? *(const bh8*)(H + (size_t)(pk2 & 0x3FFFF) * HW + l8) : z8v;
        bh8 bs2  = act ? *(const bh8*)(bsumT + (size_t)((pk2 >> 18) & 4095) * HW + l8) : z8v;
        if (act) EDGE_ACC(row, bs);
        pk = pk2; row = row2; bs = bs2;
      }
      if (act) EDGE_ACC(row, bs);
      for (u32 e = lo + 64; e < hi; ++e) {         // rare deg > 64 tail
        u32 p = eg[e];
        if (act) {
          bh8 r = *(const bh8*)(H + (size_t)(p & 0x3FFFF) * HW + l8);
          bh8 b = *(const bh8*)(bsumT + (size_t)((p >> 18) & 4095) * HW + l8);
          EDGE_ACC(r, b);
        }
      }
    }
    if (lane < 40) {                               // coalesced fragment write (16B/lane)
      u16* wp = Agg + (size_t)(n >> 6) * PANEL +
                ((size_t)((((n & 63) >> 4) * 10 + (lane >> 2)) * 64 +
                          (n & 15) * 4 + (lane & 3))) * 8;
      u32x4 o = {0u, 0u, 0u, 0u};
      if (act) {
        o[0] = cvtpk(acc[0], acc[1]); o[1] = cvtpk(acc[2], acc[3]);
        o[2] = cvtpk(acc[4], acc[5]); o[3] = cvtpk(acc[6], acc[7]);
      }
      *(u32x4*)wp = o;
    }
  }
}

// ---------------- fused per-layer MLP: Out = bn2(relu(bn1(A@W1))@W2) ----------------
// 512 threads = 8 waves; block = 64 rows. A panel (40 KB) DMA-staged into LDS once
// per block with PERMUTED global source (m173 pattern): logical chunk c of each
// 1KB group is stored at slot c^{-1} so phase-A lane l reads slot l -> byte-linear,
// ZERO bank conflicts (r21's 4M-conflict bug fixed). Staging aliases zl (consumed
// before epilogue, barrier-enforced). Swapped mfma + cvt_pk epilogues as r20.
template <int OUTBF>
__global__ __launch_bounds__(512, 4) void fused_mlp(
    const u16* __restrict__ Af, const u16* __restrict__ W1f,
    const float* __restrict__ s1, const float* __restrict__ t1,
    const u16* __restrict__ W2f, const float* __restrict__ s2,
    const float* __restrict__ t2, void* __restrict__ Out,
    int ldo, int realN, int relu2) {
  __shared__ u16 zl[MROWS * ZLD];
  const int tid = threadIdx.x, wave = tid >> 6, lane = tid & 63;
  const int lr = lane & 15, lq = lane >> 4, lk = lq * 8;
  const size_t r0 = (size_t)blockIdx.x * MROWS;
  const u16* A = Af + (size_t)blockIdx.x * PANEL;

  // ---- stage A panel into LDS: dest slot = lane (linear), source chunk = c(lane)
  // c(lane) = (lane&15)*4 + (lane>>4): the phase-A read permutation. Round i,
  // wave w stages group g = i*8+w (1KB each).
  u16* aL = zl;
  const int csrc = ((lane & 15) * 4 + (lane >> 4)) * 8;   // u16 offset of source chunk
#pragma unroll
  for (int i = 0; i < 5; ++i)                      // 5 x 512 x 16B = 40960 B
    gl16(A + i * 4096 + wave * 512 + csrc, aL + i * 4096 + tid * 8);
  __syncthreads();                                 // barrier drains DMA (vmcnt 0)

  // ---- phase A: z1 = relu(bn1(A @ W1))   (wave owns frags wave*5..+4)
  f4 acc[5][4];
#pragma unroll
  for (int i = 0; i < 5; ++i)
#pragma unroll
    for (int j = 0; j < 4; ++j) acc[i][j] = (f4){0.f, 0.f, 0.f, 0.f};
#pragma unroll
  for (int ks = 0; ks < 10; ++ks) {
    bh8 a[4];
#pragma unroll
    for (int rf = 0; rf < 4; ++rf)                 // slot = lane: conflict-free
      a[rf] = *(const bh8*)&aL[((size_t)(rf * 10 + ks) * 64 + lane) * 8];
    bh8 b[5];
#pragma unroll
    for (int cg = 0; cg < 5; ++cg) {
      const int f = wave * 5 + cg;
      if (f < 38)
        b[cg] = *(const bh8*)(W1f + ((size_t)f * 10 + ks) * 512 + lane * 8);
    }
    __builtin_amdgcn_s_setprio(1);
#pragma unroll
    for (int cg = 0; cg < 5; ++cg) {
      const int f = wave * 5 + cg;
      if (f < 38) {
#pragma unroll
        for (int rf = 0; rf < 4; ++rf) mfma16(acc[cg][rf], b[cg], a[rf]);
      }
    }
    __builtin_amdgcn_s_setprio(0);
  }
  __syncthreads();                                 // ALL waves done reading aL
  // epilogue -> zl (overwrites staging region; transposed C: rows rf*16+lr,
  // cols f*16 + lq*4 + (0..3))
#pragma unroll
  for (int cg = 0; cg < 5; ++cg) {
    const int f = wave * 5 + cg;
    if (f < 38) {
      const int colb = f * 16 + lq * 4;
      const f4 sc = *(const f4*)&s1[colb];
      const f4 sh = *(const f4*)&t1[colb];
#pragma unroll
      for (int rf = 0; rf < 4; ++rf) {
        float v0 = fmaxf(acc[cg][rf][0] * sc[0] + sh[0], 0.f);
        float v1 = fmaxf(acc[cg][rf][1] * sc[1] + sh[1], 0.f);
        float v2 = fmaxf(acc[cg][rf][2] * sc[2] + sh[2], 0.f);
        float v3 = fmaxf(acc[cg][rf][3] * sc[3] + sh[3], 0.f);
        u32x2 pk = {cvtpk(v0, v1), cvtpk(v2, v3)};
        *(u32x2*)&zl[(rf * 16 + lr) * ZLD + colb] = pk;
      }
    }
  }
  __syncthreads();

  // ---- phase B: out = bn2(z1 @ W2) (+relu)   (19 frags: waves 0-2 get 3, 3-7 get 2)
  const int cB = (wave < 3) ? 3 : 2;
  const int sB = (wave < 3) ? wave * 3 : 9 + (wave - 3) * 2;
  f4 acc2[3][4];
#pragma unroll
  for (int i = 0; i < 3; ++i)
#pragma unroll
    for (int j = 0; j < 4; ++j) acc2[i][j] = (f4){0.f, 0.f, 0.f, 0.f};
#pragma unroll
  for (int ks = 0; ks < 19; ++ks) {
    const int k0 = ks * 32;
    bh8 a[4];
#pragma unroll
    for (int rf = 0; rf < 4; ++rf)
      a[rf] = *(const bh8*)&zl[(rf * 16 + lr) * ZLD + k0 + lk];
    bh8 b[3];
#pragma unroll
    for (int cf = 0; cf < 3; ++cf)
      if (cf < cB)
        b[cf] = *(const bh8*)(W2f + ((size_t)(sB + cf) * 19 + ks) * 512 + lane * 8);
    __builtin_amdgcn_s_setprio(1);
#pragma unroll
    for (int cf = 0; cf < 3; ++cf) {
      if (cf < cB) {
#pragma unroll
        for (int rf = 0; rf < 4; ++rf) mfma16(acc2[cf][rf], b[cf], a[rf]);
      }
    }
    __builtin_amdgcn_s_setprio(0);
  }
  // transposed C: rows rf*16+lr, cols (sB+cf)*16 + lq*4 + (0..3)
#pragma unroll
  for (int cf = 0; cf < 3; ++cf) {
    if (cf < cB) {
      const int colb = (sB + cf) * 16 + lq * 4;
      if (colb + 4 <= realN) {                    // realN%4==0 -> all-or-nothing
        const f4 sc = *(const f4*)&s2[colb];
        const f4 sh = *(const f4*)&t2[colb];
#pragma unroll
        for (int rf = 0; rf < 4; ++rf) {
          const size_t row = r0 + rf * 16 + lr;
          float v0 = acc2[cf][rf][0] * sc[0] + sh[0];
          float v1 = acc2[cf][rf][1] * sc[1] + sh[1];
          float v2 = acc2[cf][rf][2] * sc[2] + sh[2];
          float v3 = acc2[cf][rf][3] * sc[3] + sh[3];
          if (relu2) {
            v0 = fmaxf(v0, 0.f); v1 = fmaxf(v1, 0.f);
            v2 = fmaxf(v2, 0.f); v3 = fmaxf(v3, 0.f);
          }
          if (OUTBF) {
            u32x2 pk = {cvtpk(v0, v1), cvtpk(v2, v3)};
            *(u32x2*)&((u16*)Out)[row * ldo + colb] = pk;
          } else {
            f4 o = {v0, v1, v2, v3};
            *(f4*)&((float*)Out)[row * ldo + colb] = o;
          }
        }
      }
    }
  }
}

// ---------------- pooling (batch sorted; range via binary search) ----------------
__device__ __forceinline__ int lbound(const int* __restrict__ b, int n, int val) {
  int lo = 0, hi = n;
  while (lo < hi) { int mid = (lo + hi) >> 1; if (b[mid] < val) lo = mid + 1; else hi = mid; }
  return lo;
}
// wave-per-graph; lanes cover cols; bh8 row loads; fragment-layout output
__global__ __launch_bounds__(256) void pool_vin(const u16* __restrict__ H,
                                                const int* __restrict__ batch,
                                                const float* __restrict__ vfeat,
                                                u16* __restrict__ vin) {
  const int wave = threadIdx.x >> 6, lane = threadIdx.x & 63;
  const int g = blockIdx.x * 4 + wave;
  if (g >= Gg) return;
  const int lo_r = lbound(batch, Nn, g), hi_r = lbound(batch, Nn, g + 1);
  const int rf = (g & 63) >> 4, lr = g & 15;
  u16* vp = vin + (size_t)(g >> 6) * PANEL +
            ((size_t)(rf * 10 + (lane >> 2)) * 64 + lr * 4 + (lane & 3)) * 8;
  if (lane < 38) {
    float acc[8];
    const float* vf = vfeat + (size_t)g * Dd + lane * 8;
    f4 v0 = *(const f4*)vf;
    f4 v1 = (lane < 37) ? *(const f4*)(vf + 4) : (f4){0.f, 0.f, 0.f, 0.f};
#pragma unroll
    for (int j = 0; j < 4; ++j) { acc[j] = v0[j]; acc[4 + j] = v1[j]; }
    for (int r = lo_r; r < hi_r; ++r) {
      bh8 hv = *(const bh8*)(H + (size_t)r * HW + lane * 8);
#pragma unroll
      for (int j = 0; j < 8; ++j) acc[j] += bf2f((u16)hv[j]);
    }
    u32x4 o;
    o[0] = cvtpk(acc[0], acc[1]); o[1] = cvtpk(acc[2], acc[3]);
    o[2] = cvtpk(acc[4], acc[5]); o[3] = cvtpk(acc[6], acc[7]);
    *(u32x4*)vp = o;
  } else if (lane < 40) {                          // k-pad 304..319 zero
    u32x4 z = {0u, 0u, 0u, 0u};
    *(u32x4*)vp = z;
  }
}
__global__ __launch_bounds__(256) void pool_out(const u16* __restrict__ H,
                                                const int* __restrict__ batch,
                                                float* __restrict__ out) {
  const int wave = threadIdx.x >> 6, lane = threadIdx.x & 63;
  const int g = blockIdx.x * 4 + wave;
  if (g >= Gg || lane >= 38) return;
  const int lo_r = lbound(batch, Nn, g), hi_r = lbound(batch, Nn, g + 1);
  float acc[8];
#pragma unroll
  for (int j = 0; j < 8; ++j) acc[j] = 0.f;
  for (int r = lo_r; r < hi_r; ++r) {
    bh8 hv = *(const bh8*)(H + (size_t)r * HW + lane * 8);
#pragma unroll
    for (int j = 0; j < 8; ++j) acc[j] += bf2f((u16)hv[j]);
  }
  float inv = 1.f / fmaxf((float)(hi_r - lo_r), 1.f);
  float* op = out + (size_t)g * Dd + lane * 8;
  f4 o0 = {acc[0] * inv, acc[1] * inv, acc[2] * inv, acc[3] * inv};
  *(f4*)op = o0;
  if (lane < 37) {
    f4 o1 = {acc[4] * inv, acc[5] * inv, acc[6] * inv, acc[7] * inv};
    *(f4*)(op + 4) = o1;
  }
}

// ---------------- pack weights into fragment layout + fold BN+bias ----------------
__global__ void pack_kernel(
    const float* __restrict__ cW1, const float* __restrict__ cb1, const float* __restrict__ cbnin,
    const float* __restrict__ cW2, const float* __restrict__ cb2, const float* __restrict__ cbnout,
    const float* __restrict__ vne, const float* __restrict__ vW1, const float* __restrict__ vb1,
    const float* __restrict__ vbn1, const float* __restrict__ vW2, const float* __restrict__ vb2,
    const float* __restrict__ vbn2,
    u16* __restrict__ W1p, u16* __restrict__ W2p, u16* __restrict__ VW1p, u16* __restrict__ VW2p,
    float* __restrict__ s1, float* __restrict__ t1, float* __restrict__ s2, float* __restrict__ t2,
    float* __restrict__ vs1, float* __restrict__ vt1, float* __restrict__ vs2, float* __restrict__ vt2,
    float* __restrict__ vfeat) {
  const int sec = blockIdx.y;
  const int stride = gridDim.x * blockDim.x;
  const int start = blockIdx.x * blockDim.x + threadIdx.x;
  if (sec == 0) {
    for (int i = start; i < NLAYER * PW1; i += stride) {
      int l = i / PW1, rm = i % PW1;
      int j = rm & 7, ln = (rm >> 3) & 63, ks = (rm >> 9) % 10, f = rm / 5120;
      int n = f * 16 + (ln & 15), k = ks * 32 + ((ln >> 4) << 3) + j;
      float v = (n < D2 && k < Dd) ? cW1[((size_t)l * Dd + k) * D2 + n] : 0.f;
      W1p[i] = f2bf(v);
    }
  } else if (sec == 1) {
    for (int i = start; i < NLAYER * PW2; i += stride) {
      int l = i / PW2, rm = i % PW2;
      int j = rm & 7, ln = (rm >> 3) & 63, ks = (rm >> 9) % 19, f = rm / 9728;
      int n = f * 16 + (ln & 15), k = ks * 32 + ((ln >> 4) << 3) + j;
      float v = (n < Dd && k < D2) ? cW2[((size_t)l * D2 + k) * Dd + n] : 0.f;
      W2p[i] = f2bf(v);
    }
  } else if (sec == 2) {
    for (int i = start; i < PW1; i += stride) {
      int j = i & 7, ln = (i >> 3) & 63, ks = (i >> 9) % 10, f = i / 5120;
      int n = f * 16 + (ln & 15), k = ks * 32 + ((ln >> 4) << 3) + j;
      float v = (n < D2 && k < Dd) ? vW1[(size_t)k * D2 + n] : 0.f;
      VW1p[i] = f2bf(v);
    }
  } else if (sec == 3) {
    for (int i = start; i < PW2; i += stride) {
      int j = i & 7, ln = (i >> 3) & 63, ks = (i >> 9) % 19, f = i / 9728;
      int n = f * 16 + (ln & 15), k = ks * 32 + ((ln >> 4) << 3) + j;
      float v = (n < Dd && k < D2) ? vW2[(size_t)k * Dd + n] : 0.f;
      VW2p[i] = f2bf(v);
    }
  } else if (sec == 4) {
    const int N1G = 640, N2G = 384;
    const int ST1 = NLAYER * N1G, ST2 = ST1 + NLAYER * N2G, ST3 = ST2 + N1G, ST4 = ST3 + N2G;
    for (int i = start; i < ST4; i += stride) {
      if (i < ST1) {
        int l = i / N1G, c = i % N1G;
        float s = 0.f, t = 0.f;
        if (c < D2) {
          float g = cbnin[(l * 4 + 0) * D2 + c], be = cbnin[(l * 4 + 1) * D2 + c];
          float m = cbnin[(l * 4 + 2) * D2 + c], va = cbnin[(l * 4 + 3) * D2 + c];
          s = g / sqrtf(va + 1e-5f);
          t = (cb1[l * D2 + c] - m) * s + be;
        }
        s1[i] = s; t1[i] = t;
      } else if (i < ST2) {
        int j = i - ST1; int l = j / N2G, c = j % N2G;
        float s = 0.f, t = 0.f;
        if (c < Dd) {
          float g = cbnout[(l * 4 + 0) * Dd + c], be = cbnout[(l * 4 + 1) * Dd + c];
          float m = cbnout[(l * 4 + 2) * Dd + c], va = cbnout[(l * 4 + 3) * Dd + c];
          s = g / sqrtf(va + 1e-5f);
          t = (cb2[l * Dd + c] - m) * s + be;
        }
        s2[j] = s; t2[j] = t;
      } else if (i < ST3) {
        int c = i - ST2;
        float s = 0.f, t = 0.f;
        if (c < D2) {
          float g = vbn1[0 * D2 + c], be = vbn1[1 * D2 + c], m = vbn1[2 * D2 + c], va = vbn1[3 * D2 + c];
          s = g / sqrtf(va + 1e-5f);
          t = (vb1[c] - m) * s + be;
        }
        vs1[c] = s; vt1[c] = t;
      } else {
        int c = i - ST3;
        float s = 0.f, t = 0.f;
        if (c < Dd) {
          float g = vbn2[0 * Dd + c], be = vbn2[1 * Dd + c], m = vbn2[2 * Dd + c], va = vbn2[3 * Dd + c];
          s = g / sqrtf(va + 1e-5f);
          t = (vb2[c] - m) * s + be;
        }
        vs2[c] = s; vt2[c] = t;
      }
    }
  } else {
    for (int i = start; i < Gg * Dd; i += stride) vfeat[i] = vne[i % Dd];
  }
}

// ---------------- launcher ----------------
extern "C" void kernel_launch(void* const* d_in, const int* in_sizes, int n_in,
                              void* d_out, int out_size, void* d_ws, size_t ws_size,
                              hipStream_t stream) {
  (void)in_sizes; (void)n_in; (void)out_size;
  const int* x      = (const int*)d_in[0];
  const int* ei     = (const int*)d_in[1];
  const int* ea     = (const int*)d_in[2];
  const int* batch  = (const int*)d_in[3];
  const float* aemb = (const float*)d_in[4];
  const float* bemb = (const float*)d_in[5];
  const float* cW1  = (const float*)d_in[6];
  const float* cb1  = (const float*)d_in[7];
  const float* cbnin  = (const float*)d_in[8];
  const float* cW2  = (const float*)d_in[9];
  const float* cb2  = (const float*)d_in[10];
  const float* cbnout = (const float*)d_in[11];
  const float* vne  = (const float*)d_in[12];
  const float* vW1  = (const float*)d_in[13];
  const float* vb1  = (const float*)d_in[14];
  const float* vbn1 = (const float*)d_in[15];
  const float* vW2  = (const float*)d_in[16];
  const float* vb2  = (const float*)d_in[17];
  const float* vbn2 = (const float*)d_in[18];
  float* out = (float*)d_out;

  // vfeat (f32, Gg x Dd = 9.6 MB) lives in d_out: fully overwritten by pool_out at the end.
  float* vfeat = out;

  char* w = (char*)d_ws;
  size_t used = 0;
  auto alloc = [&](size_t bytes) {
    char* p = w + used; used += (bytes + 255) & ~(size_t)255; return p;
  };
  u16* Ha    = (u16*)alloc((size_t)Nn * HW * 2);           // 121.6 MB: h row-major
  u16* Hb    = (u16*)alloc((size_t)(Nn / 64) * PANEL * 2); // 128.0 MB: Agg fragments
  u16* vnscr = (u16*)alloc((size_t)(Gg / 64) * PANEL * 2); // 5.12 MB: vin fragments
  u32* offs = (u32*)alloc((size_t)(Nn + 1) * 4);
  u32* eg   = (u32*)alloc((size_t)Ee * 4);
  u16* bsumT = (u16*)alloc((size_t)4096 * HW * 2);         // 2.49 MB bond-sum table
  u16* W1p  = (u16*)alloc((size_t)NLAYER * PW1 * 2);
  u16* W2p  = (u16*)alloc((size_t)NLAYER * PW2 * 2);
  u16* VW1p = (u16*)alloc((size_t)PW1 * 2);
  u16* VW2p = (u16*)alloc((size_t)PW2 * 2);
  float* s1 = (float*)alloc(NLAYER * 640 * 4);
  float* t1 = (float*)alloc(NLAYER * 640 * 4);
  float* s2 = (float*)alloc(NLAYER * 384 * 4);
  float* t2 = (float*)alloc(NLAYER * 384 * 4);
  float* vs1 = (float*)alloc(640 * 4);
  float* vt1 = (float*)alloc(640 * 4);
  float* vs2 = (float*)alloc(384 * 4);
  float* vt2 = (float*)alloc(384 * 4);

  if (used > ws_size) {   // doesn't fit -> probe reveals budget
    probe_kernel<<<1, 64, 0, stream>>>(out, (float)ws_size);
    return;
  }

  // CSR-build scratch inside Hb (dead until first gather)
  u32* counts = (u32*)Hb;
  u32* bsum   = (u32*)((char*)Hb + ((size_t)Nn * 4 + 256));
  u16* vin = vnscr;

  pack_kernel<<<dim3(96, 6), 256, 0, stream>>>(
      cW1, cb1, cbnin, cW2, cb2, cbnout, vne, vW1, vb1, vbn1, vW2, vb2, vbn2,
      W1p, W2p, VW1p, VW2p, s1, t1, s2, t2, vs1, vt1, vs2, vt2, vfeat);

  // CSR build (once; graph static across layers)
  zero_u32<<<512, 256, 0, stream>>>(counts, Nn);
  count_kernel<<<1024, 256, 0, stream>>>(ei, counts);
  scan1_kernel<<<NB_SCAN, 256, 0, stream>>>(counts, offs, bsum);
  scan2_kernel<<<1, 64, 0, stream>>>(bsum, offs);
  scan3_kernel<<<NB_SCAN, 256, 0, stream>>>(bsum, offs);
  zero_u32<<<512, 256, 0, stream>>>(counts, Nn);
  scatter_kernel<<<1024, 256, 0, stream>>>(ei, ea, offs, counts, eg);

  atom_kernel<<<ABLK, 256, 0, stream>>>(x, aemb, Ha);

  for (int l = 0; l < NLAYER; ++l) {
    if (l > 0)
      prep_kernel<<<PBLK, 256, 0, stream>>>(Ha, vfeat, batch);
    bsum_kernel<<<4096, 256, 0, stream>>>(bemb + (size_t)l * 3 * 16 * Dd, bsumT);
    // aggregate Ha -> Hb (fragment layout); fused MLP writes new h back into Ha
    gather_kernel<<<GBLK, 256, 0, stream>>>(Ha, offs, eg, bsumT, Hb);
    fused_mlp<1><<<Nn / MROWS, 512, 0, stream>>>(
        Hb, W1p + (size_t)l * PW1, s1 + l * 640, t1 + l * 640,
        W2p + (size_t)l * PW2, s2 + l * 384, t2 + l * 384,
        Ha, HW, HW, (l < 4) ? 1 : 0);
    if (l >= 1 && l <= 3) {
      pool_vin<<<Gg / 4, 256, 0, stream>>>(Ha, batch, vfeat, vin);
      fused_mlp<0><<<Gg / MROWS, 512, 0, stream>>>(
          vin, VW1p, vs1, vt1, VW2p, vs2, vt2, vfeat, Dd, Dd, 1);
    }
  }
  pool_out<<<Gg / 4, 256, 0, stream>>>(Ha, batch, out);
}

// Round 23
// 2370.714 us; speedup vs baseline: 1.0933x; 1.0933x over previous
//
#include <hip/hip_runtime.h>

// ---------------- problem constants ----------------
#define Nn 200000
#define Ee 800000
#define Dd 300
#define D2 600
#define Gg 8000
#define NLAYER 5
#define HW 304               // h stored width (bf16, row-major); cols 300..303 zero
#define K2P 608              // hidden width (gemm2 K), 600 + 8 zero pad
#define ZLD 620              // zl LDS row stride: 310 dw ≡ 22 mod 32 -> balanced banks (r16)
#define MROWS 64             // fused_mlp rows per block
#define PANEL 20480          // u16 per A-panel: 64 rows x 320 k (fragment layout)
#define PW1 194560           // u16 per layer W1f: 38 frag x 10 ks x 512
#define PW2 184832           // u16 per layer W2f: 19 frag x 19 ks x 512
#define NB_SCAN 98           // ceil(Nn / 2048)

typedef unsigned short u16;
typedef unsigned int u32;
typedef __attribute__((ext_vector_type(8))) short bh8;   // 8 x bf16
typedef __attribute__((ext_vector_type(4))) float f4;
typedef __attribute__((ext_vector_type(2))) unsigned int u32x2;
typedef __attribute__((ext_vector_type(4))) unsigned int u32x4;

__device__ __forceinline__ u16 f2bf(float f) {
  union { float f; unsigned u; } x; x.f = f;
  unsigned r = x.u + 0x7FFFu + ((x.u >> 16) & 1u);   // RNE
  return (u16)(r >> 16);
}
__device__ __forceinline__ float bf2f(u16 v) {
  union { unsigned u; float f; } x; x.u = ((unsigned)v) << 16;
  return x.f;
}
// HW packed f32->bf16 (RNE): lo -> D[15:0], hi -> D[31:16]
__device__ __forceinline__ u32 cvtpk(float lo, float hi) {
  u32 r;
  asm("v_cvt_pk_bf16_f32 %0, %1, %2" : "=v"(r) : "v"(lo), "v"(hi));
  return r;
}
__device__ __forceinline__ void mfma16(f4& c, bh8 a, bh8 b) {
  asm("v_mfma_f32_16x16x32_bf16 %0, %1, %2, %0" : "+v"(c) : "v"(a), "v"(b));
}

// ---------------- tiny utils ----------------
__global__ void zero_u32(u32* __restrict__ p, int n) {
  for (int i = blockIdx.x * blockDim.x + threadIdx.x; i < n; i += gridDim.x * blockDim.x)
    p[i] = 0u;
}
__global__ void probe_kernel(float* __restrict__ out, float v) {
  if (blockIdx.x == 0 && threadIdx.x == 0) out[0] = v;
}

// ---------------- CSR build ----------------
__global__ void count_kernel(const int* __restrict__ ei, u32* __restrict__ cnt) {
  for (int e = blockIdx.x * blockDim.x + threadIdx.x; e < Ee; e += gridDim.x * blockDim.x)
    atomicAdd(&cnt[ei[Ee + e]], 1u);
}
__global__ void scan1_kernel(const u32* __restrict__ cnt, u32* __restrict__ offs,
                             u32* __restrict__ bsum) {
  int b = blockIdx.x, t = threadIdx.x, lane = t & 63;
  int base = b * 2048 + t * 8;
  u32 v[8], s = 0;
#pragma unroll
  for (int j = 0; j < 8; ++j) { v[j] = (base + j < Nn) ? cnt[base + j] : 0u; s += v[j]; }
  u32 sc = s;
#pragma unroll
  for (int d = 1; d < 64; d <<= 1) { u32 o = __shfl_up(sc, d); if (lane >= d) sc += o; }
  __shared__ u32 swv[4];
  if (lane == 63) swv[t >> 6] = sc;
  __syncthreads();
  u32 wbase = 0;
  for (int w = 0; w < (t >> 6); ++w) wbase += swv[w];
  u32 run = wbase + sc - s;
#pragma unroll
  for (int j = 0; j < 8; ++j) {
    if (base + j < Nn) offs[base + j] = run;
    run += v[j];
  }
  if (t == 255) bsum[b] = wbase + sc;
}
__global__ void scan2_kernel(u32* __restrict__ bsum, u32* __restrict__ offs) {
  if (threadIdx.x == 0) {
    u32 run = 0;
    for (int b = 0; b < NB_SCAN; ++b) { u32 t = bsum[b]; bsum[b] = run; run += t; }
    offs[Nn] = (u32)Ee;
  }
}
__global__ void scan3_kernel(const u32* __restrict__ bsum, u32* __restrict__ offs) {
  int b = blockIdx.x;
  u32 add = bsum[b];
  int base = b * 2048 + threadIdx.x * 8;
#pragma unroll
  for (int j = 0; j < 8; ++j)
    if (base + j < Nn) offs[base + j] += add;
}
__global__ void scatter_kernel(const int* __restrict__ ei, const int* __restrict__ ea,
                               const u32* __restrict__ offs, u32* __restrict__ cur,
                               u32* __restrict__ eg) {
  for (int e = blockIdx.x * blockDim.x + threadIdx.x; e < Ee; e += gridDim.x * blockDim.x) {
    int dst = ei[Ee + e], src = ei[e];
    u32 pos = offs[dst] + atomicAdd(&cur[dst], 1u);
    eg[pos] = (u32)src | ((u32)ea[e * 3] << 18) | ((u32)ea[e * 3 + 1] << 22) |
              ((u32)ea[e * 3 + 2] << 26);
  }
}

// ---------------- per-layer bond sums: bndsum[a0+16a1+256a2][304] bf16 ----------------
__global__ void bsum_kernel(const float* __restrict__ bond, u16* __restrict__ bs) {
  int idx = blockIdx.x, tid = threadIdx.x;
  int a0 = idx & 15, a1 = (idx >> 4) & 15, a2 = idx >> 8;
  for (int c = tid; c < HW; c += 256) {
    float v = 0.f;
    if (c < Dd)
      v = bond[(size_t)a0 * Dd + c] + bond[4800 + (size_t)a1 * Dd + c] +
          bond[9600 + (size_t)a2 * Dd + c];
    bs[(size_t)idx * HW + c] = f2bf(v);
  }
}

// ---------------- atom encoder: Ha = bf16(sum_f atom_emb[f, x[n,f], :])
#define ABLK 2048
__global__ __launch_bounds__(256) void atom_kernel(const int* __restrict__ x,
                                                   const float* __restrict__ aemb,
                                                   u16* __restrict__ H) {
  const int wave = threadIdx.x >> 6, lane = threadIdx.x & 63;
  for (int n = blockIdx.x * 4 + wave; n < Nn; n += ABLK * 4) {
    if (lane < 38) {
      float lo[4] = {0.f, 0.f, 0.f, 0.f}, hi[4] = {0.f, 0.f, 0.f, 0.f};
#pragma unroll
      for (int f = 0; f < 9; ++f) {
        int xv = x[n * 9 + f];
        const float* e = aemb + (size_t)((f << 6) + xv) * Dd + lane * 8;
        f4 a = *(const f4*)e;
#pragma unroll
        for (int j = 0; j < 4; ++j) lo[j] += a[j];
        if (lane < 37) {                           // cols 300..303 stay zero (OOB guard)
          f4 b = *(const f4*)(e + 4);
#pragma unroll
          for (int j = 0; j < 4; ++j) hi[j] += b[j];
        }
      }
      u32x4 o;
      o[0] = cvtpk(lo[0], lo[1]); o[1] = cvtpk(lo[2], lo[3]);
      o[2] = cvtpk(hi[0], hi[1]); o[3] = cvtpk(hi[2], hi[3]);
      *(u32x4*)(H + (size_t)n * HW + lane * 8) = o;
    }
  }
}

// ---------------- prep: Ha += vfeat[batch]  (wave-per-node, vectorized)
#define PBLK 2048
__global__ __launch_bounds__(256) void prep_kernel(u16* __restrict__ H,
                                                   const float* __restrict__ vfeat,
                                                   const int* __restrict__ batch) {
  const int wave = threadIdx.x >> 6, lane = threadIdx.x & 63;
  for (int n = blockIdx.x * 4 + wave; n < Nn; n += PBLK * 4) {
    if (lane < 38) {
      const float* vf = vfeat + (size_t)batch[n] * Dd + lane * 8;
      u16* h = H + (size_t)n * HW + lane * 8;
      bh8 hv = *(const bh8*)h;
      f4 lo = *(const f4*)vf;                             // elems c..c+3 (<=299 ok)
      f4 hi = (lane < 37) ? *(const f4*)(vf + 4) : (f4){0.f, 0.f, 0.f, 0.f};
      union { bh8 v; u16 a[8]; } o;
#pragma unroll
      for (int j = 0; j < 4; ++j) o.a[j] = f2bf(bf2f((u16)hv[j]) + lo[j]);
#pragma unroll
      for (int j = 0; j < 4; ++j) o.a[4 + j] = f2bf(bf2f((u16)hv[4 + j]) + hi[j]);
      *(bh8*)h = o.v;
    }
  }
}

// ---------------- gather: Agg[n] = H[n] + sum_{e->n} relu(H[src]+bndsum) -> Hb
#define GBLK 2048
#define EDGE_ACC(ROW, BS)                                                             \
  {                                                                                   \
    _Pragma("unroll") for (int j = 0; j < 8; ++j) acc[j] +=                           \
        fmaxf(bf2f((u16)(ROW)[j]) + bf2f((u16)(BS)[j]), 0.f);                         \
  }
__global__ __launch_bounds__(256) void gather_kernel(
    const u16* __restrict__ H, const u32* __restrict__ offs, const u32* __restrict__ eg,
    const u16* __restrict__ bsumT, u16* __restrict__ Agg) {
  const int wave = threadIdx.x >> 6, lane = threadIdx.x & 63;
  const bool act = lane < 38;                      // 38*8 = 304 data cols
  const int l8 = lane * 8;
  const bh8 z8v = {0, 0, 0, 0, 0, 0, 0, 0};
  for (int n = blockIdx.x * 4 + wave; n < Nn; n += GBLK * 4) {
    const u32 lo = offs[n], hi = offs[n + 1];
    float acc[8];
    {
      bh8 hv = act ? *(const bh8*)(H + (size_t)n * HW + l8) : z8v;
#pragma unroll
      for (int j = 0; j < 8; ++j) acc[j] = bf2f((u16)hv[j]);
    }
    const int deg = (int)(hi - lo);
    u32 mypk = (lo + (u32)lane < hi) ? eg[lo + lane] : 0u;   // all edges in one load
    const int cnt = deg < 64 ? deg : 64;
    if (cnt > 0) {
      u32 pk = __shfl(mypk, 0);
      bh8 row = act ? *(const bh8*)(H + (size_t)(pk & 0x3FFFF) * HW + l8) : z8v;
      bh8 bs  = act ? *(const bh8*)(bsumT + (size_t)((pk >> 18) & 4095) * HW + l8) : z8v;
      for (int e = 1; e < cnt; ++e) {
        u32 pk2 = __shfl(mypk, e);
        bh8 row2 = act ? *(const bh8*)(H + (size_t)(pk2 & 0x3FFFF) * HW + l8) : z8v;
        bh8 bs2  = act ? *(const bh8*)(bsumT + (size_t)((pk2 >> 18) & 4095) * HW + l8) : z8v;
        if (act) EDGE_ACC(row, bs);
        pk = pk2; row = row2; bs = bs2;
      }
      if (act) EDGE_ACC(row, bs);
      for (u32 e = lo + 64; e < hi; ++e) {         // rare deg > 64 tail
        u32 p = eg[e];
        if (act) {
          bh8 r = *(const bh8*)(H + (size_t)(p & 0x3FFFF) * HW + l8);
          bh8 b = *(const bh8*)(bsumT + (size_t)((p >> 18) & 4095) * HW + l8);
          EDGE_ACC(r, b);
        }
      }
    }
    if (lane < 40) {                               // coalesced fragment write (16B/lane)
      u16* wp = Agg + (size_t)(n >> 6) * PANEL +
                ((size_t)((((n & 63) >> 4) * 10 + (lane >> 2)) * 64 +
                          (n & 15) * 4 + (lane & 3))) * 8;
      u32x4 o = {0u, 0u, 0u, 0u};
      if (act) {
        o[0] = cvtpk(acc[0], acc[1]); o[1] = cvtpk(acc[2], acc[3]);
        o[2] = cvtpk(acc[4], acc[5]); o[3] = cvtpk(acc[6], acc[7]);
      }
      *(u32x4*)wp = o;
    }
  }
}

// ---------------- fused per-layer MLP: Out = bn2(relu(bn1(A@W1))@W2) ----------------
// 512 threads = 8 waves; block = 64 rows. Swapped mfma operands (C transposed,
// cvt_pk epilogues). launch_bounds(512,4): <=128 regs so 2 blocks/CU (r16 lesson).
// ZLD=620: zero bank conflicts (r16). LDS A-staging tested twice (r21/r22):
// net-negative vs direct global loads -> plain per-ks loads (r20 form, session best).
template <int OUTBF>
__global__ __launch_bounds__(512, 4) void fused_mlp(
    const u16* __restrict__ Af, const u16* __restrict__ W1f,
    const float* __restrict__ s1, const float* __restrict__ t1,
    const u16* __restrict__ W2f, const float* __restrict__ s2,
    const float* __restrict__ t2, void* __restrict__ Out,
    int ldo, int realN, int relu2) {
  __shared__ u16 zl[MROWS * ZLD];
  const int tid = threadIdx.x, wave = tid >> 6, lane = tid & 63;
  const int lr = lane & 15, lq = lane >> 4, lk = lq * 8;
  const size_t r0 = (size_t)blockIdx.x * MROWS;
  const u16* A = Af + (size_t)blockIdx.x * PANEL;

  // ---- phase A: z1 = relu(bn1(A @ W1)) -> zl   (wave owns frags wave*5..+4)
  {
    f4 acc[5][4];
#pragma unroll
    for (int i = 0; i < 5; ++i)
#pragma unroll
      for (int j = 0; j < 4; ++j) acc[i][j] = (f4){0.f, 0.f, 0.f, 0.f};
#pragma unroll
    for (int ks = 0; ks < 10; ++ks) {
      bh8 a[4];
#pragma unroll
      for (int rf = 0; rf < 4; ++rf)
        a[rf] = *(const bh8*)(A + ((size_t)(rf * 10 + ks) * 64 + lr * 4 + lq) * 8);
      bh8 b[5];
#pragma unroll
      for (int cg = 0; cg < 5; ++cg) {
        const int f = wave * 5 + cg;
        if (f < 38)
          b[cg] = *(const bh8*)(W1f + ((size_t)f * 10 + ks) * 512 + lane * 8);
      }
      __builtin_amdgcn_s_setprio(1);
#pragma unroll
      for (int cg = 0; cg < 5; ++cg) {
        const int f = wave * 5 + cg;
        if (f < 38) {
#pragma unroll
          for (int rf = 0; rf < 4; ++rf) mfma16(acc[cg][rf], b[cg], a[rf]);
        }
      }
      __builtin_amdgcn_s_setprio(0);
    }
    // transposed C: thread covers rows rf*16+lr, cols f*16 + lq*4 + (0..3)
#pragma unroll
    for (int cg = 0; cg < 5; ++cg) {
      const int f = wave * 5 + cg;
      if (f < 38) {
        const int colb = f * 16 + lq * 4;
        const f4 sc = *(const f4*)&s1[colb];
        const f4 sh = *(const f4*)&t1[colb];
#pragma unroll
        for (int rf = 0; rf < 4; ++rf) {
          float v0 = fmaxf(acc[cg][rf][0] * sc[0] + sh[0], 0.f);
          float v1 = fmaxf(acc[cg][rf][1] * sc[1] + sh[1], 0.f);
          float v2 = fmaxf(acc[cg][rf][2] * sc[2] + sh[2], 0.f);
          float v3 = fmaxf(acc[cg][rf][3] * sc[3] + sh[3], 0.f);
          u32x2 pk = {cvtpk(v0, v1), cvtpk(v2, v3)};
          *(u32x2*)&zl[(rf * 16 + lr) * ZLD + colb] = pk;
        }
      }
    }
  }
  __syncthreads();

  // ---- phase B: out = bn2(z1 @ W2) (+relu)   (19 frags: waves 0-2 get 3, 3-7 get 2)
  const int cB = (wave < 3) ? 3 : 2;
  const int sB = (wave < 3) ? wave * 3 : 9 + (wave - 3) * 2;
  f4 acc2[3][4];
#pragma unroll
  for (int i = 0; i < 3; ++i)
#pragma unroll
    for (int j = 0; j < 4; ++j) acc2[i][j] = (f4){0.f, 0.f, 0.f, 0.f};
#pragma unroll
  for (int ks = 0; ks < 19; ++ks) {
    const int k0 = ks * 32;
    bh8 a[4];
#pragma unroll
    for (int rf = 0; rf < 4; ++rf)
      a[rf] = *(const bh8*)&zl[(rf * 16 + lr) * ZLD + k0 + lk];
    bh8 b[3];
#pragma unroll
    for (int cf = 0; cf < 3; ++cf)
      if (cf < cB)
        b[cf] = *(const bh8*)(W2f + ((size_t)(sB + cf) * 19 + ks) * 512 + lane * 8);
    __builtin_amdgcn_s_setprio(1);
#pragma unroll
    for (int cf = 0; cf < 3; ++cf) {
      if (cf < cB) {
#pragma unroll
        for (int rf = 0; rf < 4; ++rf) mfma16(acc2[cf][rf], b[cf], a[rf]);
      }
    }
    __builtin_amdgcn_s_setprio(0);
  }
  // transposed C: rows rf*16+lr, cols (sB+cf)*16 + lq*4 + (0..3)
#pragma unroll
  for (int cf = 0; cf < 3; ++cf) {
    if (cf < cB) {
      const int colb = (sB + cf) * 16 + lq * 4;
      if (colb + 4 <= realN) {                    // realN%4==0 -> all-or-nothing
        const f4 sc = *(const f4*)&s2[colb];
        const f4 sh = *(const f4*)&t2[colb];
#pragma unroll
        for (int rf = 0; rf < 4; ++rf) {
          const size_t row = r0 + rf * 16 + lr;
          float v0 = acc2[cf][rf][0] * sc[0] + sh[0];
          float v1 = acc2[cf][rf][1] * sc[1] + sh[1];
          float v2 = acc2[cf][rf][2] * sc[2] + sh[2];
          float v3 = acc2[cf][rf][3] * sc[3] + sh[3];
          if (relu2) {
            v0 = fmaxf(v0, 0.f); v1 = fmaxf(v1, 0.f);
            v2 = fmaxf(v2, 0.f); v3 = fmaxf(v3, 0.f);
          }
          if (OUTBF) {
            u32x2 pk = {cvtpk(v0, v1), cvtpk(v2, v3)};
            *(u32x2*)&((u16*)Out)[row * ldo + colb] = pk;
          } else {
            f4 o = {v0, v1, v2, v3};
            *(f4*)&((float*)Out)[row * ldo + colb] = o;
          }
        }
      }
    }
  }
}

// ---------------- pooling (batch sorted; range via binary search) ----------------
__device__ __forceinline__ int lbound(const int* __restrict__ b, int n, int val) {
  int lo = 0, hi = n;
  while (lo < hi) { int mid = (lo + hi) >> 1; if (b[mid] < val) lo = mid + 1; else hi = mid; }
  return lo;
}
// wave-per-graph; lanes cover cols; bh8 row loads; fragment-layout output
__global__ __launch_bounds__(256) void pool_vin(const u16* __restrict__ H,
                                                const int* __restrict__ batch,
                                                const float* __restrict__ vfeat,
                                                u16* __restrict__ vin) {
  const int wave = threadIdx.x >> 6, lane = threadIdx.x & 63;
  const int g = blockIdx.x * 4 + wave;
  if (g >= Gg) return;
  const int lo_r = lbound(batch, Nn, g), hi_r = lbound(batch, Nn, g + 1);
  const int rf = (g & 63) >> 4, lr = g & 15;
  u16* vp = vin + (size_t)(g >> 6) * PANEL +
            ((size_t)(rf * 10 + (lane >> 2)) * 64 + lr * 4 + (lane & 3)) * 8;
  if (lane < 38) {
    float acc[8];
    const float* vf = vfeat + (size_t)g * Dd + lane * 8;
    f4 v0 = *(const f4*)vf;
    f4 v1 = (lane < 37) ? *(const f4*)(vf + 4) : (f4){0.f, 0.f, 0.f, 0.f};
#pragma unroll
    for (int j = 0; j < 4; ++j) { acc[j] = v0[j]; acc[4 + j] = v1[j]; }
    for (int r = lo_r; r < hi_r; ++r) {
      bh8 hv = *(const bh8*)(H + (size_t)r * HW + lane * 8);
#pragma unroll
      for (int j = 0; j < 8; ++j) acc[j] += bf2f((u16)hv[j]);
    }
    u32x4 o;
    o[0] = cvtpk(acc[0], acc[1]); o[1] = cvtpk(acc[2], acc[3]);
    o[2] = cvtpk(acc[4], acc[5]); o[3] = cvtpk(acc[6], acc[7]);
    *(u32x4*)vp = o;
  } else if (lane < 40) {                          // k-pad 304..319 zero
    u32x4 z = {0u, 0u, 0u, 0u};
    *(u32x4*)vp = z;
  }
}
__global__ __launch_bounds__(256) void pool_out(const u16* __restrict__ H,
                                                const int* __restrict__ batch,
                                                float* __restrict__ out) {
  const int wave = threadIdx.x >> 6, lane = threadIdx.x & 63;
  const int g = blockIdx.x * 4 + wave;
  if (g >= Gg || lane >= 38) return;
  const int lo_r = lbound(batch, Nn, g), hi_r = lbound(batch, Nn, g + 1);
  float acc[8];
#pragma unroll
  for (int j = 0; j < 8; ++j) acc[j] = 0.f;
  for (int r = lo_r; r < hi_r; ++r) {
    bh8 hv = *(const bh8*)(H + (size_t)r * HW + lane * 8);
#pragma unroll
    for (int j = 0; j < 8; ++j) acc[j] += bf2f((u16)hv[j]);
  }
  float inv = 1.f / fmaxf((float)(hi_r - lo_r), 1.f);
  float* op = out + (size_t)g * Dd + lane * 8;
  f4 o0 = {acc[0] * inv, acc[1] * inv, acc[2] * inv, acc[3] * inv};
  *(f4*)op = o0;
  if (lane < 37) {
    f4 o1 = {acc[4] * inv, acc[5] * inv, acc[6] * inv, acc[7] * inv};
    *(f4*)(op + 4) = o1;
  }
}

// ---------------- pack weights into fragment layout + fold BN+bias ----------------
__global__ void pack_kernel(
    const float* __restrict__ cW1, const float* __restrict__ cb1, const float* __restrict__ cbnin,
    const float* __restrict__ cW2, const float* __restrict__ cb2, const float* __restrict__ cbnout,
    const float* __restrict__ vne, const float* __restrict__ vW1, const float* __restrict__ vb1,
    const float* __restrict__ vbn1, const float* __restrict__ vW2, const float* __restrict__ vb2,
    const float* __restrict__ vbn2,
    u16* __restrict__ W1p, u16* __restrict__ W2p, u16* __restrict__ VW1p, u16* __restrict__ VW2p,
    float* __restrict__ s1, float* __restrict__ t1, float* __restrict__ s2, float* __restrict__ t2,
    float* __restrict__ vs1, float* __restrict__ vt1, float* __restrict__ vs2, float* __restrict__ vt2,
    float* __restrict__ vfeat) {
  const int sec = blockIdx.y;
  const int stride = gridDim.x * blockDim.x;
  const int start = blockIdx.x * blockDim.x + threadIdx.x;
  if (sec == 0) {
    for (int i = start; i < NLAYER * PW1; i += stride) {
      int l = i / PW1, rm = i % PW1;
      int j = rm & 7, ln = (rm >> 3) & 63, ks = (rm >> 9) % 10, f = rm / 5120;
      int n = f * 16 + (ln & 15), k = ks * 32 + ((ln >> 4) << 3) + j;
      float v = (n < D2 && k < Dd) ? cW1[((size_t)l * Dd + k) * D2 + n] : 0.f;
      W1p[i] = f2bf(v);
    }
  } else if (sec == 1) {
    for (int i = start; i < NLAYER * PW2; i += stride) {
      int l = i / PW2, rm = i % PW2;
      int j = rm & 7, ln = (rm >> 3) & 63, ks = (rm >> 9) % 19, f = rm / 9728;
      int n = f * 16 + (ln & 15), k = ks * 32 + ((ln >> 4) << 3) + j;
      float v = (n < Dd && k < D2) ? cW2[((size_t)l * D2 + k) * Dd + n] : 0.f;
      W2p[i] = f2bf(v);
    }
  } else if (sec == 2) {
    for (int i = start; i < PW1; i += stride) {
      int j = i & 7, ln = (i >> 3) & 63, ks = (i >> 9) % 10, f = i / 5120;
      int n = f * 16 + (ln & 15), k = ks * 32 + ((ln >> 4) << 3) + j;
      float v = (n < D2 && k < Dd) ? vW1[(size_t)k * D2 + n] : 0.f;
      VW1p[i] = f2bf(v);
    }
  } else if (sec == 3) {
    for (int i = start; i < PW2; i += stride) {
      int j = i & 7, ln = (i >> 3) & 63, ks = (i >> 9) % 19, f = i / 9728;
      int n = f * 16 + (ln & 15), k = ks * 32 + ((ln >> 4) << 3) + j;
      float v = (n < Dd && k < D2) ? vW2[(size_t)k * Dd + n] : 0.f;
      VW2p[i] = f2bf(v);
    }
  } else if (sec == 4) {
    const int N1G = 640, N2G = 384;
    const int ST1 = NLAYER * N1G, ST2 = ST1 + NLAYER * N2G, ST3 = ST2 + N1G, ST4 = ST3 + N2G;
    for (int i = start; i < ST4; i += stride) {
      if (i < ST1) {
        int l = i / N1G, c = i % N1G;
        float s = 0.f, t = 0.f;
        if (c < D2) {
          float g = cbnin[(l * 4 + 0) * D2 + c], be = cbnin[(l * 4 + 1) * D2 + c];
          float m = cbnin[(l * 4 + 2) * D2 + c], va = cbnin[(l * 4 + 3) * D2 + c];
          s = g / sqrtf(va + 1e-5f);
          t = (cb1[l * D2 + c] - m) * s + be;
        }
        s1[i] = s; t1[i] = t;
      } else if (i < ST2) {
        int j = i - ST1; int l = j / N2G, c = j % N2G;
        float s = 0.f, t = 0.f;
        if (c < Dd) {
          float g = cbnout[(l * 4 + 0) * Dd + c], be = cbnout[(l * 4 + 1) * Dd + c];
          float m = cbnout[(l * 4 + 2) * Dd + c], va = cbnout[(l * 4 + 3) * Dd + c];
          s = g / sqrtf(va + 1e-5f);
          t = (cb2[l * Dd + c] - m) * s + be;
        }
        s2[j] = s; t2[j] = t;
      } else if (i < ST3) {
        int c = i - ST2;
        float s = 0.f, t = 0.f;
        if (c < D2) {
          float g = vbn1[0 * D2 + c], be = vbn1[1 * D2 + c], m = vbn1[2 * D2 + c], va = vbn1[3 * D2 + c];
          s = g / sqrtf(va + 1e-5f);
          t = (vb1[c] - m) * s + be;
        }
        vs1[c] = s; vt1[c] = t;
      } else {
        int c = i - ST3;
        float s = 0.f, t = 0.f;
        if (c < Dd) {
          float g = vbn2[0 * Dd + c], be = vbn2[1 * Dd + c], m = vbn2[2 * Dd + c], va = vbn2[3 * Dd + c];
          s = g / sqrtf(va + 1e-5f);
          t = (vb2[c] - m) * s + be;
        }
        vs2[c] = s; vt2[c] = t;
      }
    }
  } else {
    for (int i = start; i < Gg * Dd; i += stride) vfeat[i] = vne[i % Dd];
  }
}

// ---------------- launcher ----------------
extern "C" void kernel_launch(void* const* d_in, const int* in_sizes, int n_in,
                              void* d_out, int out_size, void* d_ws, size_t ws_size,
                              hipStream_t stream) {
  (void)in_sizes; (void)n_in; (void)out_size;
  const int* x      = (const int*)d_in[0];
  const int* ei     = (const int*)d_in[1];
  const int* ea     = (const int*)d_in[2];
  const int* batch  = (const int*)d_in[3];
  const float* aemb = (const float*)d_in[4];
  const float* bemb = (const float*)d_in[5];
  const float* cW1  = (const float*)d_in[6];
  const float* cb1  = (const float*)d_in[7];
  const float* cbnin  = (const float*)d_in[8];
  const float* cW2  = (const float*)d_in[9];
  const float* cb2  = (const float*)d_in[10];
  const float* cbnout = (const float*)d_in[11];
  const float* vne  = (const float*)d_in[12];
  const float* vW1  = (const float*)d_in[13];
  const float* vb1  = (const float*)d_in[14];
  const float* vbn1 = (const float*)d_in[15];
  const float* vW2  = (const float*)d_in[16];
  const float* vb2  = (const float*)d_in[17];
  const float* vbn2 = (const float*)d_in[18];
  float* out = (float*)d_out;

  // vfeat (f32, Gg x Dd = 9.6 MB) lives in d_out: fully overwritten by pool_out at the end.
  float* vfeat = out;

  char* w = (char*)d_ws;
  size_t used = 0;
  auto alloc = [&](size_t bytes) {
    char* p = w + used; used += (bytes + 255) & ~(size_t)255; return p;
  };
  u16* Ha    = (u16*)alloc((size_t)Nn * HW * 2);           // 121.6 MB: h row-major
  u16* Hb    = (u16*)alloc((size_t)(Nn / 64) * PANEL * 2); // 128.0 MB: Agg fragments
  u16* vnscr = (u16*)alloc((size_t)(Gg / 64) * PANEL * 2); // 5.12 MB: vin fragments
  u32* offs = (u32*)alloc((size_t)(Nn + 1) * 4);
  u32* eg   = (u32*)alloc((size_t)Ee * 4);
  u16* bsumT = (u16*)alloc((size_t)4096 * HW * 2);         // 2.49 MB bond-sum table
  u16* W1p  = (u16*)alloc((size_t)NLAYER * PW1 * 2);
  u16* W2p  = (u16*)alloc((size_t)NLAYER * PW2 * 2);
  u16* VW1p = (u16*)alloc((size_t)PW1 * 2);
  u16* VW2p = (u16*)alloc((size_t)PW2 * 2);
  float* s1 = (float*)alloc(NLAYER * 640 * 4);
  float* t1 = (float*)alloc(NLAYER * 640 * 4);
  float* s2 = (float*)alloc(NLAYER * 384 * 4);
  float* t2 = (float*)alloc(NLAYER * 384 * 4);
  float* vs1 = (float*)alloc(640 * 4);
  float* vt1 = (float*)alloc(640 * 4);
  float* vs2 = (float*)alloc(384 * 4);
  float* vt2 = (float*)alloc(384 * 4);

  if (used > ws_size) {   // doesn't fit -> probe reveals budget
    probe_kernel<<<1, 64, 0, stream>>>(out, (float)ws_size);
    return;
  }

  // CSR-build scratch inside Hb (dead until first gather)
  u32* counts = (u32*)Hb;
  u32* bsum   = (u32*)((char*)Hb + ((size_t)Nn * 4 + 256));
  u16* vin = vnscr;

  pack_kernel<<<dim3(96, 6), 256, 0, stream>>>(
      cW1, cb1, cbnin, cW2, cb2, cbnout, vne, vW1, vb1, vbn1, vW2, vb2, vbn2,
      W1p, W2p, VW1p, VW2p, s1, t1, s2, t2, vs1, vt1, vs2, vt2, vfeat);

  // CSR build (once; graph static across layers)
  zero_u32<<<512, 256, 0, stream>>>(counts, Nn);
  count_kernel<<<1024, 256, 0, stream>>>(ei, counts);
  scan1_kernel<<<NB_SCAN, 256, 0, stream>>>(counts, offs, bsum);
  scan2_kernel<<<1, 64, 0, stream>>>(bsum, offs);
  scan3_kernel<<<NB_SCAN, 256, 0, stream>>>(bsum, offs);
  zero_u32<<<512, 256, 0, stream>>>(counts, Nn);
  scatter_kernel<<<1024, 256, 0, stream>>>(ei, ea, offs, counts, eg);

  atom_kernel<<<ABLK, 256, 0, stream>>>(x, aemb, Ha);

  for (int l = 0; l < NLAYER; ++l) {
    if (l > 0)
      prep_kernel<<<PBLK, 256, 0, stream>>>(Ha, vfeat, batch);
    bsum_kernel<<<4096, 256, 0, stream>>>(bemb + (size_t)l * 3 * 16 * Dd, bsumT);
    // aggregate Ha -> Hb (fragment layout); fused MLP writes new h back into Ha
    gather_kernel<<<GBLK, 256, 0, stream>>>(Ha, offs, eg, bsumT, Hb);
    fused_mlp<1><<<Nn / MROWS, 512, 0, stream>>>(
        Hb, W1p + (size_t)l * PW1, s1 + l * 640, t1 + l * 640,
        W2p + (size_t)l * PW2, s2 + l * 384, t2 + l * 384,
        Ha, HW, HW, (l < 4) ? 1 : 0);
    if (l >= 1 && l <= 3) {
      pool_vin<<<Gg / 4, 256, 0, stream>>>(Ha, batch, vfeat, vin);
      fused_mlp<0><<<Gg / MROWS, 512, 0, stream>>>(
          vin, VW1p, vs1, vt1, VW2p, vs2, vt2, vfeat, Dd, Dd, 1);
    }
  }
  pool_out<<<Gg / 4, 256, 0, stream>>>(Ha, batch, out);
}